// Round 1
// baseline (669.436 us; speedup 1.0000x reference)
//
#include <hip/hip_runtime.h>
#include <hip/hip_bf16.h>

// ---------------------------------------------------------------------------
// Encoder: out = relu([features, mean_neigh(features)] @ W^T + b)
// N=100000 nodes, E=1e6 edges (undirected aggregation), D=64, H=128.
//
// ws layout: nsum = float[N*64]; deg = float[N] right after.
// ---------------------------------------------------------------------------

#define D_IN 64
#define H_OUT 128
#define NODES_PER_BLOCK 32

// One wave (64 lanes) per edge: lane i handles feature dim i.
__global__ __launch_bounds__(256) void scatter_kernel(
    const float* __restrict__ feat,
    const int* __restrict__ ei,
    float* __restrict__ nsum,
    float* __restrict__ deg,
    int E)
{
    int gid  = blockIdx.x * blockDim.x + threadIdx.x;
    int e    = gid >> 6;          // wave id = edge id
    int lane = threadIdx.x & 63;
    if (e >= E) return;

    int s = ei[e];
    int d = ei[E + e];

    float fs = feat[s * D_IN + lane];
    float fd = feat[d * D_IN + lane];

    // undirected: dst's features into src's sum, and vice versa
    atomicAdd(&nsum[s * D_IN + lane], fd);
    atomicAdd(&nsum[d * D_IN + lane], fs);
    if (lane == 0) {
        atomicAdd(&deg[s], 1.0f);
        atomicAdd(&deg[d], 1.0f);
    }
}

// Fused: mean = nsum/max(deg,1); out = relu([feat, mean] @ W^T + b).
// Block: 256 threads, 32 nodes. Two phases over k (0..63 self, 64..127 mean).
// W staged transposed in LDS as w_lds[k][h] (stride 132); 4h x 4n register tile.
__global__ __launch_bounds__(256) void combine_gemm_kernel(
    const int* __restrict__ nodes,
    const float* __restrict__ feat,
    const float* __restrict__ nsum,
    const float* __restrict__ deg,
    const float* __restrict__ W,
    const float* __restrict__ bias,
    float* __restrict__ out,
    int N)
{
    __shared__ float w_lds[64 * 132];               // [kk][h], kk in 0..63
    __shared__ float comb[NODES_PER_BLOCK * 68];    // [n][kk], padded to 68
    __shared__ float rdeg_l[NODES_PER_BLOCK];
    __shared__ int   gnode[NODES_PER_BLOCK];

    const int t  = threadIdx.x;
    const int n0 = blockIdx.x * NODES_PER_BLOCK;
    const int tx = t & 31;          // h-group: h0 = 4*tx
    const int ty = t >> 5;          // n-group: nl = 4*ty (8 groups)
    const int h0 = tx * 4;
    const int nl = ty * 4;

    if (t < NODES_PER_BLOCK) {
        int idx = n0 + t;
        if (idx >= N) idx = N - 1;
        int g = nodes[idx];
        gnode[t] = g;
        rdeg_l[t] = 1.0f / fmaxf(deg[g], 1.0f);
    }
    __syncthreads();

    float acc[4][4];
#pragma unroll
    for (int j = 0; j < 4; j++)
#pragma unroll
        for (int i = 0; i < 4; i++) acc[j][i] = 0.0f;

    for (int phase = 0; phase < 2; ++phase) {
        const int kbase = phase * 64;

        // Stage W[:, kbase:kbase+64] transposed: w_lds[kk*132 + h] = W[h][kbase+kk]
        for (int i = t; i < H_OUT * 64; i += 256) {
            int h  = i >> 6;
            int kk = i & 63;
            w_lds[kk * 132 + h] = W[h * (2 * D_IN) + kbase + kk];
        }
        // Stage combined[n][kk]: phase 0 = self features, phase 1 = neighbor mean
        for (int i = t; i < NODES_PER_BLOCK * 64; i += 256) {
            int n = i >> 6;
            int d = i & 63;
            int g = gnode[n];
            float v;
            if (phase == 0) v = feat[g * D_IN + d];
            else            v = nsum[g * D_IN + d] * rdeg_l[n];
            comb[n * 68 + d] = v;
        }
        __syncthreads();

        for (int kk = 0; kk < 64; kk += 4) {
            float4 wv[4], cv[4];
#pragma unroll
            for (int i = 0; i < 4; i++)
                wv[i] = *(const float4*)&w_lds[(kk + i) * 132 + h0];
#pragma unroll
            for (int j = 0; j < 4; j++)
                cv[j] = *(const float4*)&comb[(nl + j) * 68 + kk];
#pragma unroll
            for (int j = 0; j < 4; j++) {
                const float* c = (const float*)&cv[j];
#pragma unroll
                for (int i = 0; i < 4; i++) {
                    const float* w = (const float*)&wv[i];
                    acc[j][0] += w[0] * c[i];
                    acc[j][1] += w[1] * c[i];
                    acc[j][2] += w[2] * c[i];
                    acc[j][3] += w[3] * c[i];
                }
            }
        }
        __syncthreads();
    }

    float4 bv = *(const float4*)&bias[h0];
#pragma unroll
    for (int j = 0; j < 4; j++) {
        int n = n0 + nl + j;
        if (n >= N) continue;
        float4 o;
        o.x = fmaxf(acc[j][0] + bv.x, 0.0f);
        o.y = fmaxf(acc[j][1] + bv.y, 0.0f);
        o.z = fmaxf(acc[j][2] + bv.z, 0.0f);
        o.w = fmaxf(acc[j][3] + bv.w, 0.0f);
        *(float4*)&out[(size_t)n * H_OUT + h0] = o;
    }
}

extern "C" void kernel_launch(void* const* d_in, const int* in_sizes, int n_in,
                              void* d_out, int out_size, void* d_ws, size_t ws_size,
                              hipStream_t stream) {
    const int*   nodes = (const int*)d_in[0];
    const float* feat  = (const float*)d_in[1];
    const int*   ei    = (const int*)d_in[2];
    const float* W     = (const float*)d_in[3];
    const float* bias  = (const float*)d_in[4];
    float*       out   = (float*)d_out;

    const int N = in_sizes[0];
    const int E = in_sizes[2] / 2;

    float* nsum = (float*)d_ws;
    float* deg  = nsum + (size_t)N * D_IN;

    // harness re-poisons ws every call: zero the accumulators
    hipMemsetAsync(d_ws, 0, ((size_t)N * D_IN + N) * sizeof(float), stream);

    // one wave per edge
    int sthreads = E * 64;
    int sblocks  = (sthreads + 255) / 256;
    scatter_kernel<<<sblocks, 256, 0, stream>>>(feat, ei, nsum, deg, E);

    int gblocks = (N + NODES_PER_BLOCK - 1) / NODES_PER_BLOCK;
    combine_gemm_kernel<<<gblocks, 256, 0, stream>>>(nodes, feat, nsum, deg, W,
                                                     bias, out, N);
}

// Round 3
// 423.489 us; speedup vs baseline: 1.5808x; 1.5808x over previous
//
#include <hip/hip_runtime.h>
#include <hip/hip_bf16.h>

// ---------------------------------------------------------------------------
// Encoder: out = relu([features, mean_neigh(features)] @ W^T + b)
// N=100000, E=1e6 (undirected), D=64, H=128.
//
// Round 3 = round 2 resubmitted (container infra failure, no kernel verdict):
// bucketed adjacency build (2M int atomics on 400KB counters) + L3-resident
// gather fused into the combine/GEMM kernel. Replaces the 505us fp32-atomic
// scatter (atomic-RMW bound: 7% VALUBusy, 0 MFMA, 87% occupancy).
//
// ws layout: cnt = int[N] (memset 0 each call); adj = int[N*64] (no init
// needed: only positions < cnt are ever read).
// ---------------------------------------------------------------------------

#define D_IN 64
#define H_OUT 128
#define CAP 64            // adjacency capacity; Poisson(20) => P(deg>64)~1e-14
#define NPB 32            // nodes per block in combine kernel

__global__ __launch_bounds__(256) void build_adj_kernel(
    const int* __restrict__ ei,
    int* __restrict__ cnt,
    int* __restrict__ adj,
    int E)
{
    int e = blockIdx.x * blockDim.x + threadIdx.x;
    if (e >= E) return;
    int s = ei[e];
    int d = ei[E + e];
    // undirected: d joins s's neighbor list, s joins d's
    int ps = atomicAdd(&cnt[s], 1);
    if (ps < CAP) adj[s * CAP + ps] = d;
    int pd = atomicAdd(&cnt[d], 1);
    if (pd < CAP) adj[d * CAP + pd] = s;
}

// Fused gather + GEMM. Block: 256 threads (4 waves), 32 nodes.
// Gather: wave w handles nodes w, w+4, ...; lane = feature dim; neighbor ids
// come from ONE coalesced adjacency-row load + __shfl broadcast.
// GEMM: W staged transposed in LDS [kk][h] (stride 132); 4h x 4n reg tile.
__global__ __launch_bounds__(256) void combine_gemm_kernel(
    const int* __restrict__ nodes,
    const float* __restrict__ feat,
    const int* __restrict__ adj,
    const int* __restrict__ cnt,
    const float* __restrict__ W,
    const float* __restrict__ bias,
    float* __restrict__ out,
    int N)
{
    __shared__ float w_lds[64 * 132];        // [kk][h], one phase at a time
    __shared__ float comb_self[NPB * 68];    // [n][d] self features
    __shared__ float comb_mean[NPB * 68];    // [n][d] neighbor mean
    __shared__ int   gnode[NPB];

    const int t    = threadIdx.x;
    const int n0   = blockIdx.x * NPB;
    const int lane = t & 63;
    const int wv   = t >> 6;

    if (t < NPB) {
        int idx = n0 + t;
        if (idx >= N) idx = N - 1;
        gnode[t] = nodes[idx];
    }
    __syncthreads();

    // ---- gather phase: neighbor mean + self features into LDS ----
    for (int n = wv; n < NPB; n += 4) {
        int g  = gnode[n];      // wave-uniform (LDS broadcast)
        int c  = cnt[g];
        int cc = c < CAP ? c : CAP;
        int ids = adj[g * CAP + lane];   // lane j holds neighbor id j (j < cc)
        float sum = 0.0f;
        int j = 0;
        for (; j + 4 <= cc; j += 4) {
            int i0 = __shfl(ids, j);
            int i1 = __shfl(ids, j + 1);
            int i2 = __shfl(ids, j + 2);
            int i3 = __shfl(ids, j + 3);
            float f0 = feat[i0 * D_IN + lane];
            float f1 = feat[i1 * D_IN + lane];
            float f2 = feat[i2 * D_IN + lane];
            float f3 = feat[i3 * D_IN + lane];
            sum += (f0 + f1) + (f2 + f3);
        }
        for (; j < cc; ++j)
            sum += feat[__shfl(ids, j) * D_IN + lane];
        float rdeg = 1.0f / fmaxf((float)c, 1.0f);
        comb_mean[n * 68 + lane] = sum * rdeg;
        comb_self[n * 68 + lane] = feat[g * D_IN + lane];
    }

    // ---- stage W phase 0 (k = 0..63, self half) ----
    for (int i = t; i < H_OUT * 64; i += 256) {
        int h = i >> 6, kk = i & 63;
        w_lds[kk * 132 + h] = W[h * (2 * D_IN) + kk];
    }
    __syncthreads();

    const int tx = t & 31;
    const int ty = t >> 5;
    const int h0 = tx * 4;
    const int nl = ty * 4;

    float acc[4][4];
#pragma unroll
    for (int j = 0; j < 4; j++)
#pragma unroll
        for (int i = 0; i < 4; i++) acc[j][i] = 0.0f;

    // ---- FMA over self half ----
    for (int kk = 0; kk < 64; kk += 4) {
        float4 wvv[4], cv[4];
#pragma unroll
        for (int i = 0; i < 4; i++)
            wvv[i] = *(const float4*)&w_lds[(kk + i) * 132 + h0];
#pragma unroll
        for (int j = 0; j < 4; j++)
            cv[j] = *(const float4*)&comb_self[(nl + j) * 68 + kk];
#pragma unroll
        for (int j = 0; j < 4; j++) {
            const float* c = (const float*)&cv[j];
#pragma unroll
            for (int i = 0; i < 4; i++) {
                const float* w = (const float*)&wvv[i];
                acc[j][0] += w[0] * c[i];
                acc[j][1] += w[1] * c[i];
                acc[j][2] += w[2] * c[i];
                acc[j][3] += w[3] * c[i];
            }
        }
    }
    __syncthreads();

    // ---- stage W phase 1 (k = 64..127, mean half) ----
    for (int i = t; i < H_OUT * 64; i += 256) {
        int h = i >> 6, kk = i & 63;
        w_lds[kk * 132 + h] = W[h * (2 * D_IN) + 64 + kk];
    }
    __syncthreads();

    // ---- FMA over mean half ----
    for (int kk = 0; kk < 64; kk += 4) {
        float4 wvv[4], cv[4];
#pragma unroll
        for (int i = 0; i < 4; i++)
            wvv[i] = *(const float4*)&w_lds[(kk + i) * 132 + h0];
#pragma unroll
        for (int j = 0; j < 4; j++)
            cv[j] = *(const float4*)&comb_mean[(nl + j) * 68 + kk];
#pragma unroll
        for (int j = 0; j < 4; j++) {
            const float* c = (const float*)&cv[j];
#pragma unroll
            for (int i = 0; i < 4; i++) {
                const float* w = (const float*)&wvv[i];
                acc[j][0] += w[0] * c[i];
                acc[j][1] += w[1] * c[i];
                acc[j][2] += w[2] * c[i];
                acc[j][3] += w[3] * c[i];
            }
        }
    }

    // ---- epilogue ----
    float4 bv = *(const float4*)&bias[h0];
#pragma unroll
    for (int j = 0; j < 4; j++) {
        int n = n0 + nl + j;
        if (n >= N) continue;
        float4 o;
        o.x = fmaxf(acc[j][0] + bv.x, 0.0f);
        o.y = fmaxf(acc[j][1] + bv.y, 0.0f);
        o.z = fmaxf(acc[j][2] + bv.z, 0.0f);
        o.w = fmaxf(acc[j][3] + bv.w, 0.0f);
        *(float4*)&out[(size_t)n * H_OUT + h0] = o;
    }
}

extern "C" void kernel_launch(void* const* d_in, const int* in_sizes, int n_in,
                              void* d_out, int out_size, void* d_ws, size_t ws_size,
                              hipStream_t stream) {
    const int*   nodes = (const int*)d_in[0];
    const float* feat  = (const float*)d_in[1];
    const int*   ei    = (const int*)d_in[2];
    const float* W     = (const float*)d_in[3];
    const float* bias  = (const float*)d_in[4];
    float*       out   = (float*)d_out;

    const int N = in_sizes[0];
    const int E = in_sizes[2] / 2;

    int* cnt = (int*)d_ws;
    int* adj = cnt + N;

    // only the counters need zeroing (adj positions >= cnt are never read)
    hipMemsetAsync(cnt, 0, (size_t)N * sizeof(int), stream);

    int bblocks = (E + 255) / 256;
    build_adj_kernel<<<bblocks, 256, 0, stream>>>(ei, cnt, adj, E);

    int gblocks = (N + NPB - 1) / NPB;
    combine_gemm_kernel<<<gblocks, 256, 0, stream>>>(nodes, feat, adj, cnt, W,
                                                     bias, out, N);
}

// Round 4
// 375.984 us; speedup vs baseline: 1.7805x; 1.1263x over previous
//
#include <hip/hip_runtime.h>
#include <hip/hip_bf16.h>

// ---------------------------------------------------------------------------
// Encoder: out = relu([features, mean_neigh(features)] @ W^T + b)
// N=100000, E=1e6 (undirected), D=64, H=128.
//
// Round 4: split the fused combine kernel (190us, VALUBusy 30%, occupancy 29%
// = LDS-capped latency-bound gather) into:
//   build_adj (2E threads, 1 directed edge each)
//   aggregate (1 wave/node, NO LDS -> full occupancy; mean overwrites adj
//              row in place, ws stays 26 MB)
//   gemm      (round-3 tiled fp32 GEMM, coalesced row staging)
//
// ws layout: cnt = int[N]; adjmean = int[N*64] then float[N*64] in place.
// ---------------------------------------------------------------------------

#define D_IN 64
#define H_OUT 128
#define CAP 64            // adjacency capacity; Poisson(20) => P(deg>64)~1e-14
#define NPB 32            // nodes per block in gemm kernel

__global__ __launch_bounds__(256) void build_adj_kernel(
    const int* __restrict__ ei,
    int* __restrict__ cnt,
    int* __restrict__ adj,
    int E)
{
    int i = blockIdx.x * blockDim.x + threadIdx.x;
    if (i >= 2 * E) return;
    // i <  E: u = src_i, v = dst_i   (ei[0..E) = src, ei[E..2E) = dst)
    // i >= E: u = dst_{i-E}, v = src_{i-E}
    int u = ei[i];
    int v = (i < E) ? ei[E + i] : ei[i - E];
    int p = atomicAdd(&cnt[u], 1);
    if (p < CAP) adj[u * CAP + p] = v;
}

// One wave per node. Reads its adjacency row (coalesced 256B), gathers
// neighbor feature rows (256B each, L2/L3-resident), writes the mean row
// IN PLACE over the adjacency row (row fully consumed before the store).
__global__ __launch_bounds__(256) void aggregate_kernel(
    const float* __restrict__ feat,
    int* __restrict__ adjmean,
    const int* __restrict__ cnt,
    int N)
{
    int wid  = (blockIdx.x * blockDim.x + threadIdx.x) >> 6;  // node id
    int lane = threadIdx.x & 63;
    if (wid >= N) return;

    int c  = cnt[wid];
    int cc = c < CAP ? c : CAP;
    int ids = adjmean[wid * CAP + lane];   // lane j holds neighbor id j

    float sum = 0.0f;
    int j = 0;
    for (; j + 8 <= cc; j += 8) {
        int i0 = __shfl(ids, j + 0);
        int i1 = __shfl(ids, j + 1);
        int i2 = __shfl(ids, j + 2);
        int i3 = __shfl(ids, j + 3);
        int i4 = __shfl(ids, j + 4);
        int i5 = __shfl(ids, j + 5);
        int i6 = __shfl(ids, j + 6);
        int i7 = __shfl(ids, j + 7);
        float f0 = feat[i0 * D_IN + lane];
        float f1 = feat[i1 * D_IN + lane];
        float f2 = feat[i2 * D_IN + lane];
        float f3 = feat[i3 * D_IN + lane];
        float f4 = feat[i4 * D_IN + lane];
        float f5 = feat[i5 * D_IN + lane];
        float f6 = feat[i6 * D_IN + lane];
        float f7 = feat[i7 * D_IN + lane];
        sum += ((f0 + f1) + (f2 + f3)) + ((f4 + f5) + (f6 + f7));
    }
    for (; j < cc; ++j)
        sum += feat[__shfl(ids, j) * D_IN + lane];

    float m = sum / fmaxf((float)c, 1.0f);
    ((float*)adjmean)[wid * CAP + lane] = m;
}

// Tiled fp32 GEMM: out = relu([self||mean] @ W^T + b).
// Block: 256 threads, 32 nodes; W staged transposed in LDS [kk][h] stride 132;
// 4h x 4n register tile per thread.
__global__ __launch_bounds__(256) void gemm_kernel(
    const int* __restrict__ nodes,
    const float* __restrict__ feat,
    const float* __restrict__ mean,
    const float* __restrict__ W,
    const float* __restrict__ bias,
    float* __restrict__ out,
    int N)
{
    __shared__ float w_lds[64 * 132];        // [kk][h], one phase at a time
    __shared__ float comb_self[NPB * 68];    // [n][d]
    __shared__ float comb_mean[NPB * 68];    // [n][d]
    __shared__ int   gnode[NPB];

    const int t  = threadIdx.x;
    const int n0 = blockIdx.x * NPB;

    if (t < NPB) {
        int idx = n0 + t;
        if (idx >= N) idx = N - 1;
        gnode[t] = nodes[idx];
    }
    __syncthreads();

    // ---- stage self + mean rows (coalesced 256B rows) ----
    for (int i = t; i < NPB * 64; i += 256) {
        int n = i >> 6, d = i & 63;
        int g = gnode[n];
        comb_self[n * 68 + d] = feat[g * D_IN + d];
        comb_mean[n * 68 + d] = mean[g * D_IN + d];
    }

    // ---- stage W phase 0 (k = 0..63, self half) ----
    for (int i = t; i < H_OUT * 64; i += 256) {
        int h = i >> 6, kk = i & 63;
        w_lds[kk * 132 + h] = W[h * (2 * D_IN) + kk];
    }
    __syncthreads();

    const int tx = t & 31;
    const int ty = t >> 5;
    const int h0 = tx * 4;
    const int nl = ty * 4;

    float acc[4][4];
#pragma unroll
    for (int j = 0; j < 4; j++)
#pragma unroll
        for (int i = 0; i < 4; i++) acc[j][i] = 0.0f;

    // ---- FMA over self half ----
    for (int kk = 0; kk < 64; kk += 4) {
        float4 wvv[4], cv[4];
#pragma unroll
        for (int i = 0; i < 4; i++)
            wvv[i] = *(const float4*)&w_lds[(kk + i) * 132 + h0];
#pragma unroll
        for (int j = 0; j < 4; j++)
            cv[j] = *(const float4*)&comb_self[(nl + j) * 68 + kk];
#pragma unroll
        for (int j = 0; j < 4; j++) {
            const float* c = (const float*)&cv[j];
#pragma unroll
            for (int i = 0; i < 4; i++) {
                const float* w = (const float*)&wvv[i];
                acc[j][0] += w[0] * c[i];
                acc[j][1] += w[1] * c[i];
                acc[j][2] += w[2] * c[i];
                acc[j][3] += w[3] * c[i];
            }
        }
    }
    __syncthreads();

    // ---- stage W phase 1 (k = 64..127, mean half) ----
    for (int i = t; i < H_OUT * 64; i += 256) {
        int h = i >> 6, kk = i & 63;
        w_lds[kk * 132 + h] = W[h * (2 * D_IN) + 64 + kk];
    }
    __syncthreads();

    // ---- FMA over mean half ----
    for (int kk = 0; kk < 64; kk += 4) {
        float4 wvv[4], cv[4];
#pragma unroll
        for (int i = 0; i < 4; i++)
            wvv[i] = *(const float4*)&w_lds[(kk + i) * 132 + h0];
#pragma unroll
        for (int j = 0; j < 4; j++)
            cv[j] = *(const float4*)&comb_mean[(nl + j) * 68 + kk];
#pragma unroll
        for (int j = 0; j < 4; j++) {
            const float* c = (const float*)&cv[j];
#pragma unroll
            for (int i = 0; i < 4; i++) {
                const float* w = (const float*)&wvv[i];
                acc[j][0] += w[0] * c[i];
                acc[j][1] += w[1] * c[i];
                acc[j][2] += w[2] * c[i];
                acc[j][3] += w[3] * c[i];
            }
        }
    }

    // ---- epilogue ----
    float4 bv = *(const float4*)&bias[h0];
#pragma unroll
    for (int j = 0; j < 4; j++) {
        int n = n0 + nl + j;
        if (n >= N) continue;
        float4 o;
        o.x = fmaxf(acc[j][0] + bv.x, 0.0f);
        o.y = fmaxf(acc[j][1] + bv.y, 0.0f);
        o.z = fmaxf(acc[j][2] + bv.z, 0.0f);
        o.w = fmaxf(acc[j][3] + bv.w, 0.0f);
        *(float4*)&out[(size_t)n * H_OUT + h0] = o;
    }
}

extern "C" void kernel_launch(void* const* d_in, const int* in_sizes, int n_in,
                              void* d_out, int out_size, void* d_ws, size_t ws_size,
                              hipStream_t stream) {
    const int*   nodes = (const int*)d_in[0];
    const float* feat  = (const float*)d_in[1];
    const int*   ei    = (const int*)d_in[2];
    const float* W     = (const float*)d_in[3];
    const float* bias  = (const float*)d_in[4];
    float*       out   = (float*)d_out;

    const int N = in_sizes[0];
    const int E = in_sizes[2] / 2;

    int* cnt     = (int*)d_ws;
    int* adjmean = cnt + N;            // int[N*64], becomes float[N*64] in place

    hipMemsetAsync(cnt, 0, (size_t)N * sizeof(int), stream);

    int bblocks = (2 * E + 255) / 256;
    build_adj_kernel<<<bblocks, 256, 0, stream>>>(ei, cnt, adjmean, E);

    int ablocks = ((size_t)N * 64 + 255) / 256;
    aggregate_kernel<<<ablocks, 256, 0, stream>>>(feat, adjmean, cnt, N);

    int gblocks = (N + NPB - 1) / NPB;
    gemm_kernel<<<gblocks, 256, 0, stream>>>(nodes, feat, (const float*)adjmean,
                                             W, bias, out, N);
}

// Round 5
// 293.059 us; speedup vs baseline: 2.2843x; 1.2830x over previous
//
#include <hip/hip_runtime.h>
#include <hip/hip_bf16.h>

// ---------------------------------------------------------------------------
// Encoder: out = relu([features, mean_neigh(features)] @ W^T + b)
// N=100000, E=1e6 (undirected), D=64, H=128.
//
// Round 5:
//  (a) build_adj was partial-line HBM-write bound (WRITE_SIZE 120MB for 8MB
//      of payload, 790 GB/s drain rate = 167us): scattered 4B writes to adj
//      rows bounced lines across non-coherent per-XCD L2s. Fix: partition
//      nodes by ((u>>4)&7) and have blocks with blockIdx%8==p handle only
//      partition p (block->XCD is round-robin in practice; partitioning is
//      correctness-independent of the mapping). All writes to a cnt/adj line
//      now come from one XCD; 3.2MB slice fits its 4MB L2.
//  (b) gather volume halved: feat converted once to bf16 (12.8MB), aggregate
//      gathers 2B/lane. Mean accumulated in fp32; self half of the GEMM
//      stays exact fp32. Falls back to fp32 gather if ws is too small.
//
// ws layout: cnt = int[N]; adjmean = int[N*64] (becomes float[N*64] in
// place); fb = bf16[N*64] after adjmean (only if ws_size permits).
// ---------------------------------------------------------------------------

#define D_IN 64
#define H_OUT 128
#define CAP 64            // adjacency capacity; Poisson(20) => P(deg>64)~1e-14
#define NPB 32            // nodes per block in gemm kernel

__device__ __forceinline__ unsigned short f2bf(float f) {
    __hip_bfloat16 h = __float2bfloat16(f);
    return *reinterpret_cast<unsigned short*>(&h);
}
__device__ __forceinline__ float bf2f(unsigned short u) {
    unsigned int x = ((unsigned int)u) << 16;
    return __uint_as_float(x);
}

// XCD-partitioned adjacency build. Directed edge i (i<E: u=src,v=dst;
// i>=E: u=dst,v=src). Note u == ei[i] in both cases.
__global__ __launch_bounds__(256) void build_adj_kernel(
    const int* __restrict__ ei,
    int* __restrict__ cnt,
    int* __restrict__ adj,
    int E)
{
    const int part   = blockIdx.x & 7;       // presumed XCD (round-robin)
    const int bloc   = blockIdx.x >> 3;      // block index within partition
    const int nbp    = gridDim.x >> 3;       // blocks per partition
    const int stride = nbp * 256;
    const int E2     = 2 * E;

    for (int i = bloc * 256 + (int)threadIdx.x; i < E2; i += stride) {
        int u = ei[i];
        if (((u >> 4) & 7) != part) continue;   // one cnt line per group of 16
        int v = (i < E) ? ei[E + i] : ei[i - E];
        int p = atomicAdd(&cnt[u], 1);
        if (p < CAP) adj[u * CAP + p] = v;
    }
}

__global__ __launch_bounds__(256) void feat_to_bf16_kernel(
    const float4* __restrict__ f4,
    ushort4* __restrict__ out,
    int n4)
{
    int i = blockIdx.x * 256 + threadIdx.x;
    if (i >= n4) return;
    float4 v = f4[i];
    ushort4 o;
    o.x = f2bf(v.x); o.y = f2bf(v.y); o.z = f2bf(v.z); o.w = f2bf(v.w);
    out[i] = o;
}

// One wave per node, zero LDS (full occupancy). bf16 feature gather,
// fp32 accumulate; mean overwrites the adjacency row in place.
__global__ __launch_bounds__(256) void aggregate_bf16_kernel(
    const unsigned short* __restrict__ fb,
    int* __restrict__ adjmean,
    const int* __restrict__ cnt,
    int N)
{
    int wid  = (blockIdx.x * blockDim.x + threadIdx.x) >> 6;
    int lane = threadIdx.x & 63;
    if (wid >= N) return;

    int c  = cnt[wid];
    int cc = c < CAP ? c : CAP;
    int ids = adjmean[wid * CAP + lane];

    float sum = 0.0f;
    int j = 0;
    for (; j + 8 <= cc; j += 8) {
        int i0 = __shfl(ids, j + 0);
        int i1 = __shfl(ids, j + 1);
        int i2 = __shfl(ids, j + 2);
        int i3 = __shfl(ids, j + 3);
        int i4 = __shfl(ids, j + 4);
        int i5 = __shfl(ids, j + 5);
        int i6 = __shfl(ids, j + 6);
        int i7 = __shfl(ids, j + 7);
        float f0 = bf2f(fb[i0 * D_IN + lane]);
        float f1 = bf2f(fb[i1 * D_IN + lane]);
        float f2 = bf2f(fb[i2 * D_IN + lane]);
        float f3 = bf2f(fb[i3 * D_IN + lane]);
        float f4 = bf2f(fb[i4 * D_IN + lane]);
        float f5 = bf2f(fb[i5 * D_IN + lane]);
        float f6 = bf2f(fb[i6 * D_IN + lane]);
        float f7 = bf2f(fb[i7 * D_IN + lane]);
        sum += ((f0 + f1) + (f2 + f3)) + ((f4 + f5) + (f6 + f7));
    }
    for (; j < cc; ++j)
        sum += bf2f(fb[__shfl(ids, j) * D_IN + lane]);

    float m = sum / fmaxf((float)c, 1.0f);
    ((float*)adjmean)[wid * CAP + lane] = m;
}

// fp32 fallback (only used if ws_size can't hold the bf16 copy).
__global__ __launch_bounds__(256) void aggregate_f32_kernel(
    const float* __restrict__ feat,
    int* __restrict__ adjmean,
    const int* __restrict__ cnt,
    int N)
{
    int wid  = (blockIdx.x * blockDim.x + threadIdx.x) >> 6;
    int lane = threadIdx.x & 63;
    if (wid >= N) return;

    int c  = cnt[wid];
    int cc = c < CAP ? c : CAP;
    int ids = adjmean[wid * CAP + lane];

    float sum = 0.0f;
    int j = 0;
    for (; j + 8 <= cc; j += 8) {
        int i0 = __shfl(ids, j + 0);
        int i1 = __shfl(ids, j + 1);
        int i2 = __shfl(ids, j + 2);
        int i3 = __shfl(ids, j + 3);
        int i4 = __shfl(ids, j + 4);
        int i5 = __shfl(ids, j + 5);
        int i6 = __shfl(ids, j + 6);
        int i7 = __shfl(ids, j + 7);
        float f0 = feat[i0 * D_IN + lane];
        float f1 = feat[i1 * D_IN + lane];
        float f2 = feat[i2 * D_IN + lane];
        float f3 = feat[i3 * D_IN + lane];
        float f4 = feat[i4 * D_IN + lane];
        float f5 = feat[i5 * D_IN + lane];
        float f6 = feat[i6 * D_IN + lane];
        float f7 = feat[i7 * D_IN + lane];
        sum += ((f0 + f1) + (f2 + f3)) + ((f4 + f5) + (f6 + f7));
    }
    for (; j < cc; ++j)
        sum += feat[__shfl(ids, j) * D_IN + lane];

    float m = sum / fmaxf((float)c, 1.0f);
    ((float*)adjmean)[wid * CAP + lane] = m;
}

// Tiled fp32 GEMM: out = relu([self||mean] @ W^T + b).
__global__ __launch_bounds__(256) void gemm_kernel(
    const int* __restrict__ nodes,
    const float* __restrict__ feat,
    const float* __restrict__ mean,
    const float* __restrict__ W,
    const float* __restrict__ bias,
    float* __restrict__ out,
    int N)
{
    __shared__ float w_lds[64 * 132];        // [kk][h], one phase at a time
    __shared__ float comb_self[NPB * 68];    // [n][d]
    __shared__ float comb_mean[NPB * 68];    // [n][d]
    __shared__ int   gnode[NPB];

    const int t  = threadIdx.x;
    const int n0 = blockIdx.x * NPB;

    if (t < NPB) {
        int idx = n0 + t;
        if (idx >= N) idx = N - 1;
        gnode[t] = nodes[idx];
    }
    __syncthreads();

    for (int i = t; i < NPB * 64; i += 256) {
        int n = i >> 6, d = i & 63;
        int g = gnode[n];
        comb_self[n * 68 + d] = feat[g * D_IN + d];
        comb_mean[n * 68 + d] = mean[g * D_IN + d];
    }
    for (int i = t; i < H_OUT * 64; i += 256) {
        int h = i >> 6, kk = i & 63;
        w_lds[kk * 132 + h] = W[h * (2 * D_IN) + kk];
    }
    __syncthreads();

    const int tx = t & 31;
    const int ty = t >> 5;
    const int h0 = tx * 4;
    const int nl = ty * 4;

    float acc[4][4];
#pragma unroll
    for (int j = 0; j < 4; j++)
#pragma unroll
        for (int i = 0; i < 4; i++) acc[j][i] = 0.0f;

    for (int kk = 0; kk < 64; kk += 4) {
        float4 wvv[4], cv[4];
#pragma unroll
        for (int i = 0; i < 4; i++)
            wvv[i] = *(const float4*)&w_lds[(kk + i) * 132 + h0];
#pragma unroll
        for (int j = 0; j < 4; j++)
            cv[j] = *(const float4*)&comb_self[(nl + j) * 68 + kk];
#pragma unroll
        for (int j = 0; j < 4; j++) {
            const float* c = (const float*)&cv[j];
#pragma unroll
            for (int i = 0; i < 4; i++) {
                const float* w = (const float*)&wvv[i];
                acc[j][0] += w[0] * c[i];
                acc[j][1] += w[1] * c[i];
                acc[j][2] += w[2] * c[i];
                acc[j][3] += w[3] * c[i];
            }
        }
    }
    __syncthreads();

    for (int i = t; i < H_OUT * 64; i += 256) {
        int h = i >> 6, kk = i & 63;
        w_lds[kk * 132 + h] = W[h * (2 * D_IN) + 64 + kk];
    }
    __syncthreads();

    for (int kk = 0; kk < 64; kk += 4) {
        float4 wvv[4], cv[4];
#pragma unroll
        for (int i = 0; i < 4; i++)
            wvv[i] = *(const float4*)&w_lds[(kk + i) * 132 + h0];
#pragma unroll
        for (int j = 0; j < 4; j++)
            cv[j] = *(const float4*)&comb_mean[(nl + j) * 68 + kk];
#pragma unroll
        for (int j = 0; j < 4; j++) {
            const float* c = (const float*)&cv[j];
#pragma unroll
            for (int i = 0; i < 4; i++) {
                const float* w = (const float*)&wvv[i];
                acc[j][0] += w[0] * c[i];
                acc[j][1] += w[1] * c[i];
                acc[j][2] += w[2] * c[i];
                acc[j][3] += w[3] * c[i];
            }
        }
    }

    float4 bv = *(const float4*)&bias[h0];
#pragma unroll
    for (int j = 0; j < 4; j++) {
        int n = n0 + nl + j;
        if (n >= N) continue;
        float4 o;
        o.x = fmaxf(acc[j][0] + bv.x, 0.0f);
        o.y = fmaxf(acc[j][1] + bv.y, 0.0f);
        o.z = fmaxf(acc[j][2] + bv.z, 0.0f);
        o.w = fmaxf(acc[j][3] + bv.w, 0.0f);
        *(float4*)&out[(size_t)n * H_OUT + h0] = o;
    }
}

extern "C" void kernel_launch(void* const* d_in, const int* in_sizes, int n_in,
                              void* d_out, int out_size, void* d_ws, size_t ws_size,
                              hipStream_t stream) {
    const int*   nodes = (const int*)d_in[0];
    const float* feat  = (const float*)d_in[1];
    const int*   ei    = (const int*)d_in[2];
    const float* W     = (const float*)d_in[3];
    const float* bias  = (const float*)d_in[4];
    float*       out   = (float*)d_out;

    const int N = in_sizes[0];
    const int E = in_sizes[2] / 2;

    int* cnt     = (int*)d_ws;
    int* adjmean = cnt + N;                      // int[N*CAP] -> float in place
    unsigned short* fb = (unsigned short*)(adjmean + (size_t)N * CAP);

    const size_t need_bf16 = (size_t)N * 4 + (size_t)N * CAP * 4
                           + (size_t)N * D_IN * 2;
    const bool use_bf16 = (ws_size >= need_bf16);   // launch-constant branch

    hipMemsetAsync(cnt, 0, (size_t)N * sizeof(int), stream);

    build_adj_kernel<<<2048, 256, 0, stream>>>(ei, cnt, adjmean, E);

    int ablocks = ((size_t)N * 64 + 255) / 256;
    if (use_bf16) {
        int n4 = N * D_IN / 4;
        feat_to_bf16_kernel<<<(n4 + 255) / 256, 256, 0, stream>>>(
            (const float4*)feat, (ushort4*)fb, n4);
        aggregate_bf16_kernel<<<ablocks, 256, 0, stream>>>(fb, adjmean, cnt, N);
    } else {
        aggregate_f32_kernel<<<ablocks, 256, 0, stream>>>(feat, adjmean, cnt, N);
    }

    int gblocks = (N + NPB - 1) / NPB;
    gemm_kernel<<<gblocks, 256, 0, stream>>>(nodes, feat, (const float*)adjmean,
                                             W, bias, out, N);
}